// Round 2
// baseline (227.255 us; speedup 1.0000x reference)
//
#include <hip/hip_runtime.h>
#include <math.h>

#define NB 4
#define NH 8
#define DD 64
#define LL 2048
#define CC 64
#define QB 128
#define KB 64
#define NW 8
#define EPS 1e-5

typedef __attribute__((ext_vector_type(4))) float f32x4;
typedef __attribute__((ext_vector_type(8))) short bf16x8;
typedef __attribute__((ext_vector_type(2))) unsigned int u32x2;

__device__ __forceinline__ unsigned short f2bf(float f) {
  unsigned int u = __builtin_bit_cast(unsigned int, f);
  u += 0x7fffu + ((u >> 16) & 1u);   // round-to-nearest-even
  return (unsigned short)(u >> 16);
}
__device__ __forceinline__ unsigned int pack2(float a, float b) {
  return (unsigned int)f2bf(a) | ((unsigned int)f2bf(b) << 16);
}

// block-reduce two floats, atomically add into doubles
__device__ __forceinline__ void reduce2_atomic(float s, float ss,
                                               double* dS, double* dSS,
                                               float* red, int nw) {
#pragma unroll
  for (int off = 32; off > 0; off >>= 1) {
    s += __shfl_xor(s, off);
    ss += __shfl_xor(ss, off);
  }
  const int t = threadIdx.x;
  if ((t & 63) == 0) { red[t >> 6] = s; red[8 + (t >> 6)] = ss; }
  __syncthreads();
  if (t == 0) {
    float S = 0.f, SS = 0.f;
    for (int w = 0; w < nw; ++w) { S += red[w]; SS += red[8 + w]; }
    atomicAdd(dS, (double)S);
    atomicAdd(dSS, (double)SS);
  }
}

// ---------------- Pass 1: per-batch sum / sumsq of sim = Q^T K ----------------
__global__ __launch_bounds__(512, 1) void sim_stats_kernel(
    const float* __restrict__ qg, const float* __restrict__ kg,
    double* __restrict__ s1, double* __restrict__ s1sq) {
  __shared__ short qt[QB * DD];   // [l][d] bf16, swizzled
  __shared__ short kt[KB * DD];   // [m][d] bf16, swizzled
  __shared__ float red[16];

  const int blk = blockIdx.x;
  const int lblk = blk & (LL / QB - 1);
  const int bh = blk >> 4;
  const int b = bh >> 3;
  const int l0 = lblk * QB;

  const float* qbase = qg + (size_t)bh * DD * LL;
  const float* kbase = kg + (size_t)bh * DD * LL;

  const int t = threadIdx.x;
  const int lane = t & 63;
  const int wid = t >> 6;
  const int g = lane >> 4;
  const int ln = lane & 15;

  // stage Q tile transposed: qt[l][d] = bf16(q[d][l0+l])
  {
    const int l = t & 127;
    const int dg = (t >> 7) << 2;
#pragma unroll
    for (int it = 0; it < 4; ++it) {
      const int d0 = it * 16 + dg;
      float f0 = qbase[(size_t)(d0 + 0) * LL + l0 + l];
      float f1 = qbase[(size_t)(d0 + 1) * LL + l0 + l];
      float f2 = qbase[(size_t)(d0 + 2) * LL + l0 + l];
      float f3 = qbase[(size_t)(d0 + 3) * LL + l0 + l];
      const int idx = (l * DD + d0) ^ ((l & 7) << 3);
      u32x2 w = {pack2(f0, f1), pack2(f2, f3)};
      *(u32x2*)&qt[idx] = w;
    }
  }
  __syncthreads();

  // Q fragments (B-operand): lane holds q[l = wid*16+ln][d = kc*32 + g*8 + e]
  bf16x8 qf[2];
#pragma unroll
  for (int kc = 0; kc < 2; ++kc) {
    const int l = wid * 16 + ln;
    const int d = kc * 32 + g * 8;
    qf[kc] = *(const bf16x8*)&qt[(l * DD + d) ^ ((l & 7) << 3)];
  }

  float ssum = 0.f, ssq = 0.f;

  for (int mt = 0; mt < LL / KB; ++mt) {
    const int m0 = mt * KB;
    __syncthreads();
    {
      const int m = t & 63;
      const int dg = ((t >> 6) & 7) << 2;
#pragma unroll
      for (int it = 0; it < 2; ++it) {
        const int d0 = it * 32 + dg;
        float f0 = kbase[(size_t)(d0 + 0) * LL + m0 + m];
        float f1 = kbase[(size_t)(d0 + 1) * LL + m0 + m];
        float f2 = kbase[(size_t)(d0 + 2) * LL + m0 + m];
        float f3 = kbase[(size_t)(d0 + 3) * LL + m0 + m];
        const int idx = (m * DD + d0) ^ ((m & 7) << 3);
        u32x2 w = {pack2(f0, f1), pack2(f2, f3)};
        *(u32x2*)&kt[idx] = w;
      }
    }
    __syncthreads();

#pragma unroll
    for (int mf = 0; mf < 4; ++mf) {
      f32x4 acc = {0.f, 0.f, 0.f, 0.f};
#pragma unroll
      for (int kc = 0; kc < 2; ++kc) {
        const int m = mf * 16 + ln;
        const int d = kc * 32 + g * 8;
        bf16x8 kf = *(const bf16x8*)&kt[(m * DD + d) ^ ((m & 7) << 3)];
        acc = __builtin_amdgcn_mfma_f32_16x16x32_bf16(kf, qf[kc], acc, 0, 0, 0);
      }
#pragma unroll
      for (int r = 0; r < 4; ++r) { ssum += acc[r]; ssq += acc[r] * acc[r]; }
    }
  }
  __syncthreads();
  reduce2_atomic(ssum, ssq, &s1[b], &s1sq[b], red, NW);
}

// ---------------- finalize pass-1 stats -> per-batch logit scale ----------------
__global__ void finalize1_kernel(const double* __restrict__ s1,
                                 const double* __restrict__ s1sq,
                                 float* __restrict__ scale1) {
  const int b = threadIdx.x;
  if (b < NB) {
    const double cnt = (double)NH * (double)LL * (double)LL;
    const double mean = s1[b] / cnt;
    const double var = s1sq[b] / cnt - mean * mean;
    scale1[b] = (float)(1.0 / sqrt(var + EPS));
  }
}

// ---------------- Pass 2: flash attention with per-batch logit scale ----------------
__global__ __launch_bounds__(512, 1) void attn_kernel(
    const float* __restrict__ qg, const float* __restrict__ kg,
    const float* __restrict__ vg, float* __restrict__ rv,
    const float* __restrict__ scale1,
    double* __restrict__ s2, double* __restrict__ s2sq) {
  __shared__ short qt[QB * DD];      // [l][d] swizzled
  __shared__ short kt[KB * DD];      // [m][d] swizzled
  __shared__ short vt[CC * 72];      // [c][m], padded stride 72
  __shared__ short pb[NW * 16 * 72]; // per-wave P [16][72]
  __shared__ float red[16];

  const int blk = blockIdx.x;
  const int lblk = blk & (LL / QB - 1);
  const int bh = blk >> 4;
  const int b = bh >> 3;
  const int l0 = lblk * QB;

  const float* qbase = qg + (size_t)bh * DD * LL;
  const float* kbase = kg + (size_t)bh * DD * LL;
  const float* vbase = vg + (size_t)bh * CC * LL;

  const int t = threadIdx.x;
  const int lane = t & 63;
  const int wid = t >> 6;
  const int g = lane >> 4;
  const int ln = lane & 15;

  const float sc = scale1[b];

  // stage Q tile transposed
  {
    const int l = t & 127;
    const int dg = (t >> 7) << 2;
#pragma unroll
    for (int it = 0; it < 4; ++it) {
      const int d0 = it * 16 + dg;
      float f0 = qbase[(size_t)(d0 + 0) * LL + l0 + l];
      float f1 = qbase[(size_t)(d0 + 1) * LL + l0 + l];
      float f2 = qbase[(size_t)(d0 + 2) * LL + l0 + l];
      float f3 = qbase[(size_t)(d0 + 3) * LL + l0 + l];
      const int idx = (l * DD + d0) ^ ((l & 7) << 3);
      u32x2 w = {pack2(f0, f1), pack2(f2, f3)};
      *(u32x2*)&qt[idx] = w;
    }
  }
  __syncthreads();

  bf16x8 qf[2];
#pragma unroll
  for (int kc = 0; kc < 2; ++kc) {
    const int l = wid * 16 + ln;
    const int d = kc * 32 + g * 8;
    qf[kc] = *(const bf16x8*)&qt[(l * DD + d) ^ ((l & 7) << 3)];
  }

  f32x4 o[4];
#pragma unroll
  for (int cf = 0; cf < 4; ++cf) o[cf] = (f32x4){0.f, 0.f, 0.f, 0.f};
  float mrun = -INFINITY, lrun = 0.f;

  short* pw = pb + wid * (16 * 72);

  for (int mt = 0; mt < LL / KB; ++mt) {
    const int m0 = mt * KB;
    __syncthreads();
    // stage K (transposed, swizzled) and V (straight, padded)
    {
      const int m = t & 63;
      const int dg = ((t >> 6) & 7) << 2;
#pragma unroll
      for (int it = 0; it < 2; ++it) {
        const int d0 = it * 32 + dg;
        float f0 = kbase[(size_t)(d0 + 0) * LL + m0 + m];
        float f1 = kbase[(size_t)(d0 + 1) * LL + m0 + m];
        float f2 = kbase[(size_t)(d0 + 2) * LL + m0 + m];
        float f3 = kbase[(size_t)(d0 + 3) * LL + m0 + m];
        const int idx = (m * DD + d0) ^ ((m & 7) << 3);
        u32x2 w = {pack2(f0, f1), pack2(f2, f3)};
        *(u32x2*)&kt[idx] = w;
      }
      const int c = t >> 4;            // 0..31
      const int m4 = (t & 15) << 2;
#pragma unroll
      for (int it = 0; it < 2; ++it) {
        const int cc = it * 32 + c;
        f32x4 f = *(const f32x4*)&vbase[(size_t)cc * LL + m0 + m4];
        u32x2 w = {pack2(f[0], f[1]), pack2(f[2], f[3])};
        *(u32x2*)&vt[cc * 72 + m4] = w;
      }
    }
    __syncthreads();

    // S^T tile: lane holds S[l = wid*16+ln][m = mf*16 + g*4 + r]
    f32x4 s[4];
#pragma unroll
    for (int mf = 0; mf < 4; ++mf) {
      f32x4 acc = {0.f, 0.f, 0.f, 0.f};
#pragma unroll
      for (int kc = 0; kc < 2; ++kc) {
        const int m = mf * 16 + ln;
        const int d = kc * 32 + g * 8;
        bf16x8 kf = *(const bf16x8*)&kt[(m * DD + d) ^ ((m & 7) << 3)];
        acc = __builtin_amdgcn_mfma_f32_16x16x32_bf16(kf, qf[kc], acc, 0, 0, 0);
      }
      s[mf] = acc;
    }

    // online softmax (row = ln, all 64 lanes active)
    float tmax = -INFINITY;
#pragma unroll
    for (int mf = 0; mf < 4; ++mf)
#pragma unroll
      for (int r = 0; r < 4; ++r) {
        s[mf][r] *= sc;
        tmax = fmaxf(tmax, s[mf][r]);
      }
    tmax = fmaxf(tmax, __shfl_xor(tmax, 16));
    tmax = fmaxf(tmax, __shfl_xor(tmax, 32));
    const float mnew = fmaxf(mrun, tmax);
    const float corr = __expf(mrun - mnew);
    float tsum = 0.f;
#pragma unroll
    for (int mf = 0; mf < 4; ++mf)
#pragma unroll
      for (int r = 0; r < 4; ++r) {
        const float p = __expf(s[mf][r] - mnew);
        s[mf][r] = p;
        tsum += p;
      }
    tsum += __shfl_xor(tsum, 16);
    tsum += __shfl_xor(tsum, 32);
    lrun = lrun * corr + tsum;
    mrun = mnew;

    // write P (bf16) to wave-private LDS: pw[row ln][m]
#pragma unroll
    for (int mf = 0; mf < 4; ++mf) {
      u32x2 w = {pack2(s[mf][0], s[mf][1]), pack2(s[mf][2], s[mf][3])};
      *(u32x2*)&pw[ln * 72 + mf * 16 + g * 4] = w;
    }
    asm volatile("s_waitcnt lgkmcnt(0)" ::: "memory");
    __builtin_amdgcn_sched_barrier(0);

    // rescale O (rows l' = g*4 + r live in different lanes than softmax rows)
#pragma unroll
    for (int r = 0; r < 4; ++r) {
      const float cr = __shfl(corr, g * 4 + r);
#pragma unroll
      for (int cf = 0; cf < 4; ++cf) o[cf][r] *= cr;
    }

    // PV: O[l][c] += P[l][m] * V^T[m][c]
#pragma unroll
    for (int mk = 0; mk < 2; ++mk) {
      bf16x8 pf = *(const bf16x8*)&pw[ln * 72 + mk * 32 + g * 8];
#pragma unroll
      for (int cf = 0; cf < 4; ++cf) {
        bf16x8 vf = *(const bf16x8*)&vt[(cf * 16 + ln) * 72 + mk * 32 + g * 8];
        o[cf] = __builtin_amdgcn_mfma_f32_16x16x32_bf16(pf, vf, o[cf], 0, 0, 0);
      }
    }
  }

  // normalize by softmax denom, write rv (= d_out), accumulate LN2 stats
  float inv[4];
#pragma unroll
  for (int r = 0; r < 4; ++r) inv[r] = 1.0f / __shfl(lrun, g * 4 + r);

  float ssum = 0.f, ssq = 0.f;
  const int lout = l0 + wid * 16 + g * 4;
#pragma unroll
  for (int cf = 0; cf < 4; ++cf) {
    f32x4 ov;
#pragma unroll
    for (int r = 0; r < 4; ++r) {
      const float x = o[cf][r] * inv[r];
      ov[r] = x;
      ssum += x;
      ssq += x * x;
    }
    const int c = cf * 16 + ln;
    *(f32x4*)&rv[((size_t)bh * CC + c) * LL + lout] = ov;
  }
  __syncthreads();
  reduce2_atomic(ssum, ssq, &s2[b], &s2sq[b], red, NW);
}

// ---------------- Pass 3: LayerNorm over (H*C, L) per batch + exact GELU ----------------
__global__ __launch_bounds__(256) void ln_gelu_kernel(
    float* __restrict__ out, const double* __restrict__ s2,
    const double* __restrict__ s2sq) {
  const size_t i = ((size_t)blockIdx.x * 256 + threadIdx.x) * 4;
  const int b = (int)(i >> 20);  // H*C*L = 2^20 per batch
  const double cnt = (double)(NH * CC) * (double)LL;
  const double mean = s2[b] / cnt;
  const double var = s2sq[b] / cnt - mean * mean;
  const float invs = (float)(1.0 / sqrt(var + EPS));
  const float mu = (float)mean;
  f32x4 x = *(f32x4*)&out[i];
#pragma unroll
  for (int r = 0; r < 4; ++r) {
    const float z = (x[r] - mu) * invs;
    x[r] = 0.5f * z * (1.0f + erff(z * 0.70710678118f));
  }
  *(f32x4*)&out[i] = x;
}

extern "C" void kernel_launch(void* const* d_in, const int* in_sizes, int n_in,
                              void* d_out, int out_size, void* d_ws, size_t ws_size,
                              hipStream_t stream) {
  (void)in_sizes; (void)n_in; (void)out_size; (void)ws_size;
  const float* q = (const float*)d_in[0];
  const float* k = (const float*)d_in[1];
  const float* v = (const float*)d_in[2];
  float* out = (float*)d_out;

  double* s1 = (double*)d_ws;
  double* s1sq = s1 + NB;
  double* s2 = s1 + 2 * NB;
  double* s2sq = s1 + 3 * NB;
  float* scale1 = (float*)(s1 + 4 * NB);

  hipMemsetAsync(d_ws, 0, 4 * NB * sizeof(double) + NB * sizeof(float), stream);

  const int nblk = NB * NH * (LL / QB);  // 512
  sim_stats_kernel<<<dim3(nblk), dim3(512), 0, stream>>>(q, k, s1, s1sq);
  finalize1_kernel<<<dim3(1), dim3(64), 0, stream>>>(s1, s1sq, scale1);
  attn_kernel<<<dim3(nblk), dim3(512), 0, stream>>>(q, k, v, out, scale1, s2, s2sq);
  ln_gelu_kernel<<<dim3((NB * NH * CC * LL) / (4 * 256)), dim3(256), 0, stream>>>(out, s2, s2sq);
}

// Round 4
// 203.100 us; speedup vs baseline: 1.1189x; 1.1189x over previous
//
#include <hip/hip_runtime.h>
#include <math.h>

#define NB 4
#define NH 8
#define DD 64
#define LL 2048
#define CC 64
#define QB 128
#define KB 64
#define EPS 1e-5

typedef __attribute__((ext_vector_type(4))) float f32x4;
typedef __attribute__((ext_vector_type(8))) short bf16x8;
typedef __attribute__((ext_vector_type(2))) unsigned int u32x2;
typedef __attribute__((ext_vector_type(4))) unsigned int u32x4;

// truncate two f32 to bf16 and pack into one u32 (single v_perm_b32)
__device__ __forceinline__ unsigned packtrunc(float a, float b) {
  return __builtin_amdgcn_perm(__builtin_bit_cast(unsigned, b),
                               __builtin_bit_cast(unsigned, a), 0x07060302u);
}
__device__ __forceinline__ bf16x8 pack8(f32x4 a, f32x4 b) {
  u32x4 u = {packtrunc(a[0], a[1]), packtrunc(a[2], a[3]),
             packtrunc(b[0], b[1]), packtrunc(b[2], b[3])};
  return __builtin_bit_cast(bf16x8, u);
}

// block-reduce two floats, atomically add into doubles (nw waves)
__device__ __forceinline__ void reduce2_atomic(float s, float ss,
                                               double* dS, double* dSS,
                                               float* red, int nw) {
#pragma unroll
  for (int off = 32; off > 0; off >>= 1) {
    s += __shfl_xor(s, off);
    ss += __shfl_xor(ss, off);
  }
  const int t = threadIdx.x;
  if ((t & 63) == 0) { red[t >> 6] = s; red[8 + (t >> 6)] = ss; }
  __syncthreads();
  if (t == 0) {
    float S = 0.f, SS = 0.f;
    for (int w = 0; w < nw; ++w) { S += red[w]; SS += red[8 + w]; }
    atomicAdd(dS, (double)S);
    atomicAdd(dSS, (double)SS);
  }
}

// ---------- Pass 1: Gram-matrix stats.  Σsim² = Σ_{d,d'} Gq·Gk, Σsim = Σq·Σk ----------
// grid 512: (bh, 4x4 d-tile).  Fragments straight from global (no LDS staging).
__global__ __launch_bounds__(512, 1) void gram_kernel(
    const float* __restrict__ qg, const float* __restrict__ kg,
    float* __restrict__ sumv, double* __restrict__ ssqd) {
  __shared__ float lsw[8][2][256];  // per-wave partial 16x16 tiles (q,k)

  const int phys = blockIdx.x;
  const int blk = ((phys & 7) << 6) | (phys >> 3);  // XCD-chunked, bijective (512%8==0)
  const int bh = blk >> 4;
  const int tile = blk & 15;
  const int ti = tile >> 2, tj = tile & 3;
  const int b = bh >> 3;

  const float* qb = qg + (size_t)bh * DD * LL;
  const float* kb = kg + (size_t)bh * DD * LL;

  const int t = threadIdx.x;
  const int lane = t & 63;
  const int w = t >> 6;
  const int g = lane >> 4;
  const int ln = lane & 15;
  const int ri = ti * 16 + ln, rj = tj * 16 + ln;

  f32x4 aq = {0.f, 0.f, 0.f, 0.f}, ak = {0.f, 0.f, 0.f, 0.f};
  float sq = 0.f, sk = 0.f;

#pragma unroll 1
  for (int st = 0; st < 8; ++st) {
    const int l0 = w * 256 + st * 32 + g * 8;
    f32x4 qi0 = *(const f32x4*)&qb[(size_t)ri * LL + l0];
    f32x4 qi1 = *(const f32x4*)&qb[(size_t)ri * LL + l0 + 4];
    f32x4 qj0 = *(const f32x4*)&qb[(size_t)rj * LL + l0];
    f32x4 qj1 = *(const f32x4*)&qb[(size_t)rj * LL + l0 + 4];
    f32x4 ki0 = *(const f32x4*)&kb[(size_t)ri * LL + l0];
    f32x4 ki1 = *(const f32x4*)&kb[(size_t)ri * LL + l0 + 4];
    f32x4 kj0 = *(const f32x4*)&kb[(size_t)rj * LL + l0];
    f32x4 kj1 = *(const f32x4*)&kb[(size_t)rj * LL + l0 + 4];
    aq = __builtin_amdgcn_mfma_f32_16x16x32_bf16(pack8(qi0, qi1), pack8(qj0, qj1), aq, 0, 0, 0);
    ak = __builtin_amdgcn_mfma_f32_16x16x32_bf16(pack8(ki0, ki1), pack8(kj0, kj1), ak, 0, 0, 0);
    if (ti == tj) {
#pragma unroll
      for (int e = 0; e < 4; ++e) { sq += qi0[e] + qi1[e]; sk += ki0[e] + ki1[e]; }
    }
  }

#pragma unroll
  for (int r = 0; r < 4; ++r) {
    lsw[w][0][(g * 4 + r) * 16 + ln] = aq[r];
    lsw[w][1][(g * 4 + r) * 16 + ln] = ak[r];
  }
  if (ti == tj) {
    sq += __shfl_xor(sq, 16); sq += __shfl_xor(sq, 32);
    sk += __shfl_xor(sk, 16); sk += __shfl_xor(sk, 32);
    if (lane < 16) {
      atomicAdd(&sumv[bh * DD + ti * 16 + ln], sq);
      atomicAdd(&sumv[2048 + bh * DD + ti * 16 + ln], sk);
    }
  }
  __syncthreads();

  float prod = 0.f;
  if (t < 256) {
    float gq = 0.f, gk = 0.f;
#pragma unroll
    for (int ww = 0; ww < 8; ++ww) { gq += lsw[ww][0][t]; gk += lsw[ww][1][t]; }
    prod = gq * gk;
  }
#pragma unroll
  for (int off = 1; off < 64; off <<= 1) prod += __shfl_xor(prod, off);
  if (t < 256 && lane == 0) atomicAdd(&ssqd[b], (double)prod);
}

// ---------- finalize stats -> per-batch logit scale (includes log2(e)) ----------
__global__ void fin_kernel(const double* __restrict__ ssqd,
                           const float* __restrict__ sumv,
                           float* __restrict__ scale2) {
  const int t = threadIdx.x, lane = t & 63, b = t >> 6;
  float part = 0.f;
#pragma unroll
  for (int j = 0; j < 8; ++j) {
    const int idx = j * 64 + lane;      // 0..511 = (h,d)
    const int bh = b * 8 + (idx >> 6);
    const int d = idx & 63;
    part += sumv[bh * 64 + d] * sumv[2048 + bh * 64 + d];
  }
#pragma unroll
  for (int off = 1; off < 64; off <<= 1) part += __shfl_xor(part, off);
  if (lane == 0) {
    const double cnt = 33554432.0;  // NH*LL*LL
    const double mu = (double)part / cnt;
    const double var = ssqd[b] / cnt - mu * mu;
    scale2[b] = (float)(1.4426950408889634 / sqrt(var + EPS));
  }
}

// ---------- Pass 2: flash attention, fixed-max exp2 softmax ----------
// 256 threads = 4 waves, each wave owns 32 q-rows.
__global__ __launch_bounds__(256, 2) void attn_kernel(
    const float* __restrict__ qg, const float* __restrict__ kg,
    const float* __restrict__ vg, float* __restrict__ rv,
    const float* __restrict__ scale2,
    double* __restrict__ s2, double* __restrict__ s2sq) {
  __shared__ short kt[KB * DD];   // [m][d] bf16, 16B-granule swizzle ^(m&7)
  __shared__ short vt[CC * KB];   // [c][m] bf16, swizzle ^(c&7)
  __shared__ short qp[QB * DD];   // Q [l][d] swizzled; reused per-wave as P buffer
  __shared__ float red[16];

  const int phys = blockIdx.x;
  const int blk = ((phys & 7) << 6) | (phys >> 3);  // XCD-chunked
  const int lblk = blk & 15;
  const int bh = blk >> 4;
  const int b = bh >> 3;
  const int l0 = lblk * QB;

  const float* qbase = qg + (size_t)bh * DD * LL;
  const float* kbase = kg + (size_t)bh * DD * LL;
  const float* vbase = vg + (size_t)bh * CC * LL;

  const int t = threadIdx.x;
  const int lane = t & 63;
  const int wid = t >> 6;
  const int g = lane >> 4;
  const int ln = lane & 15;
  const float sc2 = scale2[b];

  // ---- stage Q tile transposed (trunc bf16) ----
  {
    const int l = t & 127;
    const int db = (t >> 7) << 5;  // 0 / 32
#pragma unroll
    for (int it = 0; it < 8; ++it) {
      const int d0 = db + it * 4;
      float f0 = qbase[(size_t)(d0 + 0) * LL + l0 + l];
      float f1 = qbase[(size_t)(d0 + 1) * LL + l0 + l];
      float f2 = qbase[(size_t)(d0 + 2) * LL + l0 + l];
      float f3 = qbase[(size_t)(d0 + 3) * LL + l0 + l];
      u32x2 wq = {packtrunc(f0, f1), packtrunc(f2, f3)};
      *(u32x2*)&qp[(l * DD + d0) ^ ((l & 7) << 3)] = wq;
    }
  }
  __syncthreads();

  bf16x8 qf[2][2];
#pragma unroll
  for (int rb = 0; rb < 2; ++rb)
#pragma unroll
    for (int kc = 0; kc < 2; ++kc) {
      const int l = wid * 32 + rb * 16 + ln;
      qf[rb][kc] = *(const bf16x8*)&qp[(l * DD + kc * 32 + g * 8) ^ ((l & 7) << 3)];
    }

  short* pw = qp + wid * 2048;  // wave-private P region (overlaps own Q rows, already consumed)

  f32x4 o[2][4];
#pragma unroll
  for (int rb = 0; rb < 2; ++rb)
#pragma unroll
    for (int cf = 0; cf < 4; ++cf) o[rb][cf] = (f32x4){0.f, 0.f, 0.f, 0.f};
  float lacc[2] = {0.f, 0.f};

  float kr[2][16];
  f32x4 vr[2][4];

  auto LOADT = [&](int cur, int mt) {
    const int m0 = mt * KB;
    const int m = t & 63;
    const int db2 = wid * 4;
#pragma unroll
    for (int it = 0; it < 4; ++it) {
      const int d0 = it * 16 + db2;
#pragma unroll
      for (int j = 0; j < 4; ++j)
        kr[cur][it * 4 + j] = kbase[(size_t)(d0 + j) * LL + m0 + m];
    }
    const int cb = t >> 4;          // 0..15
    const int m4 = (t & 15) * 4;
#pragma unroll
    for (int it = 0; it < 4; ++it)
      vr[cur][it] = *(const f32x4*)&vbase[(size_t)(it * 16 + cb) * LL + m0 + m4];
  };

  auto CVTW = [&](int cur) {
    const int m = t & 63;
    const int db2 = wid * 4;
#pragma unroll
    for (int it = 0; it < 4; ++it) {
      const int d0 = it * 16 + db2;
      u32x2 wk = {packtrunc(kr[cur][it * 4 + 0], kr[cur][it * 4 + 1]),
                  packtrunc(kr[cur][it * 4 + 2], kr[cur][it * 4 + 3])};
      *(u32x2*)&kt[(m * DD + d0) ^ ((m & 7) << 3)] = wk;
    }
    const int cb = t >> 4;
    const int m4 = (t & 15) * 4;
#pragma unroll
    for (int it = 0; it < 4; ++it) {
      const int cc = it * 16 + cb;
      f32x4 f = vr[cur][it];
      u32x2 wv = {packtrunc(f[0], f[1]), packtrunc(f[2], f[3])};
      *(u32x2*)&vt[(cc * KB + m4) ^ ((cc & 7) << 3)] = wv;
    }
  };

  auto COMPUTE = [&]() {
    f32x4 s[2][4];
#pragma unroll
    for (int mf = 0; mf < 4; ++mf) {
      const int m = mf * 16 + ln;
      const bf16x8 ka = *(const bf16x8*)&kt[(m * DD + g * 8) ^ ((m & 7) << 3)];
      const bf16x8 kb2 = *(const bf16x8*)&kt[(m * DD + 32 + g * 8) ^ ((m & 7) << 3)];
      f32x4 z = {0.f, 0.f, 0.f, 0.f};
      s[0][mf] = __builtin_amdgcn_mfma_f32_16x16x32_bf16(ka, qf[0][0], z, 0, 0, 0);
      s[0][mf] = __builtin_amdgcn_mfma_f32_16x16x32_bf16(kb2, qf[0][1], s[0][mf], 0, 0, 0);
      s[1][mf] = __builtin_amdgcn_mfma_f32_16x16x32_bf16(ka, qf[1][0], z, 0, 0, 0);
      s[1][mf] = __builtin_amdgcn_mfma_f32_16x16x32_bf16(kb2, qf[1][1], s[1][mf], 0, 0, 0);
    }
    // p = exp2(z * sc2), fixed max (logits are globally std-normalized)
#pragma unroll
    for (int rb = 0; rb < 2; ++rb) {
      const int rr = rb * 16 + ln;
#pragma unroll
      for (int mf = 0; mf < 4; ++mf) {
        f32x4 p;
#pragma unroll
        for (int r = 0; r < 4; ++r) {
          p[r] = __builtin_exp2f(s[rb][mf][r] * sc2);
          lacc[rb] += p[r];
        }
        u32x2 wp = {packtrunc(p[0], p[1]), packtrunc(p[2], p[3])};
        *(u32x2*)&pw[(rr * KB + mf * 16 + g * 4) ^ ((rr & 7) << 3)] = wp;
      }
    }
    asm volatile("s_waitcnt lgkmcnt(0)" ::: "memory");
    __builtin_amdgcn_sched_barrier(0);
    // PV
#pragma unroll
    for (int mk = 0; mk < 2; ++mk) {
      bf16x8 pf[2];
#pragma unroll
      for (int rb = 0; rb < 2; ++rb) {
        const int rr = rb * 16 + ln;
        pf[rb] = *(const bf16x8*)&pw[(rr * KB + mk * 32 + g * 8) ^ ((rr & 7) << 3)];
      }
#pragma unroll
      for (int cf = 0; cf < 4; ++cf) {
        const int c = cf * 16 + ln;
        const bf16x8 vf = *(const bf16x8*)&vt[(c * KB + mk * 32 + g * 8) ^ ((c & 7) << 3)];
        o[0][cf] = __builtin_amdgcn_mfma_f32_16x16x32_bf16(pf[0], vf, o[0][cf], 0, 0, 0);
        o[1][cf] = __builtin_amdgcn_mfma_f32_16x16x32_bf16(pf[1], vf, o[1][cf], 0, 0, 0);
      }
    }
  };

  LOADT(0, 0);
#pragma unroll 1
  for (int mt2 = 0; mt2 < 16; ++mt2) {
    // even tile
    __builtin_amdgcn_s_barrier();              // all waves done reading previous tile
    asm volatile("" ::: "memory");
    CVTW(0);
    LOADT(1, mt2 * 2 + 1);                     // prefetch next (hides under compute)
    __builtin_amdgcn_sched_barrier(0);
    asm volatile("s_waitcnt lgkmcnt(0)" ::: "memory");
    __builtin_amdgcn_s_barrier();              // staging visible to all waves
    asm volatile("" ::: "memory");
    COMPUTE();
    // odd tile
    __builtin_amdgcn_s_barrier();
    asm volatile("" ::: "memory");
    CVTW(1);
    if (mt2 < 15) LOADT(0, mt2 * 2 + 2);
    __builtin_amdgcn_sched_barrier(0);
    asm volatile("s_waitcnt lgkmcnt(0)" ::: "memory");
    __builtin_amdgcn_s_barrier();
    asm volatile("" ::: "memory");
    COMPUTE();
  }

  // row denominators: lane-local partials -> cross-lane reduce once
  float inv[2][4];
#pragma unroll
  for (int rb = 0; rb < 2; ++rb) {
    float ls = lacc[rb];
    ls += __shfl_xor(ls, 16);
    ls += __shfl_xor(ls, 32);
#pragma unroll
    for (int r = 0; r < 4; ++r) inv[rb][r] = 1.0f / __shfl(ls, g * 4 + r);
  }

  float ssum = 0.f, ssq = 0.f;
#pragma unroll
  for (int rb = 0; rb < 2; ++rb) {
    const int lout = l0 + wid * 32 + rb * 16 + g * 4;
#pragma unroll
    for (int cf = 0; cf < 4; ++cf) {
      f32x4 ov;
#pragma unroll
      for (int r = 0; r < 4; ++r) {
        const float x = o[rb][cf][r] * inv[rb][r];
        ov[r] = x;
        ssum += x;
        ssq += x * x;
      }
      *(f32x4*)&rv[((size_t)(bh * CC + cf * 16 + ln)) * LL + lout] = ov;
    }
  }
  __syncthreads();
  reduce2_atomic(ssum, ssq, &s2[b], &s2sq[b], red, 4);
}

// ---------- Pass 3: LayerNorm over (H*C, L) per batch + exact GELU ----------
__global__ __launch_bounds__(256) void ln_gelu_kernel(
    float* __restrict__ out, const double* __restrict__ s2,
    const double* __restrict__ s2sq) {
  const size_t i = ((size_t)blockIdx.x * 256 + threadIdx.x) * 4;
  const int b = (int)(i >> 20);  // H*C*L = 2^20 per batch
  const double cnt = (double)(NH * CC) * (double)LL;
  const double mean = s2[b] / cnt;
  const double var = s2sq[b] / cnt - mean * mean;
  const float invs = (float)(1.0 / sqrt(var + EPS));
  const float mu = (float)mean;
  f32x4 x = *(f32x4*)&out[i];
#pragma unroll
  for (int r = 0; r < 4; ++r) {
    const float z = (x[r] - mu) * invs;
    x[r] = 0.5f * z * (1.0f + erff(z * 0.70710678118f));
  }
  *(f32x4*)&out[i] = x;
}

extern "C" void kernel_launch(void* const* d_in, const int* in_sizes, int n_in,
                              void* d_out, int out_size, void* d_ws, size_t ws_size,
                              hipStream_t stream) {
  (void)in_sizes; (void)n_in; (void)out_size; (void)ws_size;
  const float* q = (const float*)d_in[0];
  const float* k = (const float*)d_in[1];
  const float* v = (const float*)d_in[2];
  float* out = (float*)d_out;

  double* dssq = (double*)d_ws;      // [4]
  double* ds2 = dssq + 4;            // [4]
  double* ds2sq = dssq + 8;          // [4]
  float* sumv = (float*)(dssq + 12); // [2*32*64]
  float* scale2 = sumv + 4096;       // [4]

  hipMemsetAsync(d_ws, 0, 12 * 8 + 4096 * 4 + 4 * 4, stream);

  gram_kernel<<<dim3(512), dim3(512), 0, stream>>>(q, k, sumv, dssq);
  fin_kernel<<<dim3(1), dim3(256), 0, stream>>>(dssq, sumv, scale2);
  attn_kernel<<<dim3(512), dim3(256), 0, stream>>>(q, k, v, out, scale2, ds2, ds2sq);
  ln_gelu_kernel<<<dim3((NB * NH * CC * LL) / (4 * 256)), dim3(256), 0, stream>>>(out, ds2, ds2sq);
}